// Round 2
// baseline (1146.531 us; speedup 1.0000x reference)
//
#include <hip/hip_runtime.h>

#define EPS 1e-10f
#define NITERS 20
#define NN (1024*1024)

typedef __attribute__((ext_vector_type(8))) short bf16x8;
typedef __attribute__((ext_vector_type(4))) float f32x4;

__device__ __forceinline__ unsigned short f2bf(float f) {
  unsigned int x = __builtin_bit_cast(unsigned int, f);
  x += 0x7fffu + ((x >> 16) & 1u);   // round-to-nearest-even
  return (unsigned short)(x >> 16);
}

// K = exp(log_alpha + gumbel(u)) = exp(la) / (EPS - log(u + EPS)); also init u-potential to 1.
__global__ __launch_bounds__(256) void gumbel_k(const float4* __restrict__ u4,
                                                const float4* __restrict__ la4,
                                                float4* __restrict__ K4,
                                                float* __restrict__ uu) {
  int gid = blockIdx.x * 256 + threadIdx.x;      // 8,388,608 float4s
  float4 uv = u4[gid];
  float4 la = la4[gid & (NN/4 - 1)];
  float4 o;
  o.x = expf(la.x) / (EPS - logf(uv.x + EPS));
  o.y = expf(la.y) / (EPS - logf(uv.y + EPS));
  o.z = expf(la.z) / (EPS - logf(uv.z + EPS));
  o.w = expf(la.w) / (EPS - logf(uv.w + EPS));
  K4[gid] = o;
  if (gid < 8192) ((float4*)uu)[gid] = make_float4(1.f, 1.f, 1.f, 1.f);
}

__global__ __launch_bounds__(256) void cvt_x(const float4* __restrict__ x4,
                                             unsigned short* __restrict__ xb) {
  int gid = blockIdx.x * 256 + threadIdx.x;      // 2,097,152 float4s
  float4 v = x4[gid];
  ushort4 o;
  o.x = f2bf(v.x); o.y = f2bf(v.y); o.z = f2bf(v.z); o.w = f2bf(v.w);
  *(ushort4*)&xb[(size_t)gid * 4] = o;
}

// Column half-iteration: partial sums of K^T * u over 256-row chunks.
// grid 512: bx -> rc (row chunk, &3), cb (col block of 256, >>2 &3), sb (>>4)
__global__ __launch_bounds__(256) void col_pass(const float* __restrict__ K,
                                                const float* __restrict__ uu,
                                                float* __restrict__ pv) {
  int bx = blockIdx.x;
  int rc = bx & 3, cb = (bx >> 2) & 3, sb = bx >> 4;
  const float* Kb = K + (size_t)sb * NN;
  const float* u = uu + (sb << 10);
  int tid = threadIdx.x, l = tid & 63, w = tid >> 6;
  int j0 = cb * 256 + l * 4;
  float4 acc = make_float4(0.f, 0.f, 0.f, 0.f);
  int iend = rc * 256 + 256;
  for (int i = rc * 256 + w; i < iend; i += 4) {
    float4 kk = *(const float4*)&Kb[(size_t)i * 1024 + j0];
    float ui = u[i];
    acc.x += kk.x * ui; acc.y += kk.y * ui; acc.z += kk.z * ui; acc.w += kk.w * ui;
  }
  __shared__ float4 red[4][64];
  red[w][l] = acc;
  __syncthreads();
  if (tid < 64) {
    float4 a = red[0][tid], b = red[1][tid], c = red[2][tid], d = red[3][tid];
    float4 s;
    s.x = a.x + b.x + c.x + d.x; s.y = a.y + b.y + c.y + d.y;
    s.z = a.z + b.z + c.z + d.z; s.w = a.w + b.w + c.w + d.w;
    *(float4*)&pv[(size_t)rc * 32768 + (sb << 10) + cb * 256 + tid * 4] = s;
  }
}

__global__ __launch_bounds__(256) void col_reduce(const float4* __restrict__ pv4,
                                                  float4* __restrict__ vv4) {
  int gid = blockIdx.x * 256 + threadIdx.x;      // 8192
  float4 a = pv4[gid], b = pv4[gid + 8192], c = pv4[gid + 16384], d = pv4[gid + 24576];
  float4 r;
  r.x = 1.f / (a.x + b.x + c.x + d.x);
  r.y = 1.f / (a.y + b.y + c.y + d.y);
  r.z = 1.f / (a.z + b.z + c.z + d.z);
  r.w = 1.f / (a.w + b.w + c.w + d.w);
  vv4[gid] = r;
}

// Row half-iteration: u_i = 1 / sum_j K_ij v_j. One wave per row.
__global__ __launch_bounds__(256) void row_pass(const float* __restrict__ K,
                                                const float* __restrict__ vv,
                                                float* __restrict__ uu) {
  int bx = blockIdx.x;                            // 8192
  int sb = bx >> 8, rb = bx & 255;
  int tid = threadIdx.x, l = tid & 63, w = tid >> 6;
  int i = (rb << 2) + w;
  const float* Kr = K + (size_t)sb * NN + (size_t)i * 1024;
  const float* v = vv + (sb << 10);
  float acc = 0.f;
#pragma unroll
  for (int s = 0; s < 4; ++s) {
    int j = (s << 8) + (l << 2);
    float4 kk = *(const float4*)&Kr[j];
    float4 v4 = *(const float4*)&v[j];
    acc += kk.x * v4.x + kk.y * v4.y + kk.z * v4.z + kk.w * v4.w;
  }
#pragma unroll
  for (int m = 32; m; m >>= 1) acc += __shfl_xor(acc, m, 64);
  if (l == 0) uu[(sb << 10) + i] = 1.0f / acc;
}

// P^T in bf16 via 64x64 LDS tile transpose: Pt[m][n] = K[n][m]*u[n]*v[m]
__global__ __launch_bounds__(256) void make_pt(const float* __restrict__ K,
                                               const float* __restrict__ uu,
                                               const float* __restrict__ vv,
                                               unsigned short* __restrict__ Pt) {
  int bx = blockIdx.x;                            // 8192
  int sb = bx >> 8, t = bx & 255;
  int n0 = (t >> 4) << 6, m0 = (t & 15) << 6;
  const float* Kb = K + (size_t)sb * NN;
  const float* u = uu + (sb << 10);
  const float* v = vv + (sb << 10);
  unsigned short* Pb = Pt + (size_t)sb * NN;
  __shared__ unsigned short tile[64][68];
  int tid = threadIdx.x, c = tid & 63, r4 = tid >> 6;
#pragma unroll
  for (int p = 0; p < 16; ++p) {
    int rr = (p << 2) + r4;
    float val = Kb[(size_t)(n0 + rr) * 1024 + m0 + c] * u[n0 + rr] * v[m0 + c];
    tile[rr][c] = f2bf(val);
  }
  __syncthreads();
#pragma unroll
  for (int p = 0; p < 16; ++p) {
    int rr = (p << 2) + r4;
    Pb[(size_t)(m0 + rr) * 1024 + n0 + c] = tile[c][rr];
  }
}

// C[d][m] = sum_n A[d][n] * B[n][m], A = x_bf16 (row-major, k contig),
// Bt = P^T (row m, k=n contig). 128x128 tile, 4 waves, 16x16x32 MFMA.
__global__ __launch_bounds__(256) void gemm_bf16(const unsigned short* __restrict__ xb,
                                                 const unsigned short* __restrict__ Pt,
                                                 float* __restrict__ out) {
  int sb = blockIdx.y;
  int b = sb & 7;
  int tm = blockIdx.x >> 3;
  int tn = blockIdx.x & 7;
  const unsigned short* A = xb + (size_t)b * NN;
  const unsigned short* Bt = Pt + (size_t)sb * NN;
  float* C = out + (size_t)sb * NN;

  __shared__ unsigned short lA[128 * 32];
  __shared__ unsigned short lB[128 * 32];

  int tid = threadIdx.x;
  int lane = tid & 63;
  int w = tid >> 6;
  int wm = (w >> 1) << 6;
  int wn = (w & 1) << 6;

  f32x4 acc[4][4] = {};

  int lr = tid >> 2;
  int lk = (tid & 3) << 3;
  const unsigned short* gA0 = A + (size_t)(tm * 128 + lr) * 1024 + lk;
  const unsigned short* gB0 = Bt + (size_t)(tn * 128 + lr) * 1024 + lk;

  for (int k0 = 0; k0 < 1024; k0 += 32) {
    __builtin_amdgcn_global_load_lds((const __attribute__((address_space(1))) void*)(gA0 + k0),
                                     (__attribute__((address_space(3))) void*)&lA[tid * 8], 16, 0, 0);
    __builtin_amdgcn_global_load_lds((const __attribute__((address_space(1))) void*)(gA0 + 64 * 1024 + k0),
                                     (__attribute__((address_space(3))) void*)&lA[2048 + tid * 8], 16, 0, 0);
    __builtin_amdgcn_global_load_lds((const __attribute__((address_space(1))) void*)(gB0 + k0),
                                     (__attribute__((address_space(3))) void*)&lB[tid * 8], 16, 0, 0);
    __builtin_amdgcn_global_load_lds((const __attribute__((address_space(1))) void*)(gB0 + 64 * 1024 + k0),
                                     (__attribute__((address_space(3))) void*)&lB[2048 + tid * 8], 16, 0, 0);
    __syncthreads();   // drains vmcnt -> LDS tile ready

    int kg = (lane >> 4) << 3;
    int rr = lane & 15;
    bf16x8 af[4], bfr[4];
#pragma unroll
    for (int mt = 0; mt < 4; ++mt)
      af[mt] = *(const bf16x8*)&lA[(wm + mt * 16 + rr) * 32 + kg];
#pragma unroll
    for (int nt = 0; nt < 4; ++nt)
      bfr[nt] = *(const bf16x8*)&lB[(wn + nt * 16 + rr) * 32 + kg];
#pragma unroll
    for (int mt = 0; mt < 4; ++mt)
#pragma unroll
      for (int nt = 0; nt < 4; ++nt)
        acc[mt][nt] = __builtin_amdgcn_mfma_f32_16x16x32_bf16(af[mt], bfr[nt], acc[mt][nt], 0, 0, 0);
    __syncthreads();   // protect LDS before next stage
  }

  int col0 = lane & 15;
  int row0 = (lane >> 4) << 2;
#pragma unroll
  for (int mt = 0; mt < 4; ++mt) {
#pragma unroll
    for (int nt = 0; nt < 4; ++nt) {
      int row = tm * 128 + wm + mt * 16 + row0;
      int col = tn * 128 + wn + nt * 16 + col0;
#pragma unroll
      for (int r = 0; r < 4; ++r)
        C[(size_t)(row + r) * 1024 + col] = acc[mt][nt][r];
    }
  }
}

extern "C" void kernel_launch(void* const* d_in, const int* in_sizes, int n_in,
                              void* d_out, int out_size, void* d_ws, size_t ws_size,
                              hipStream_t stream) {
  (void)in_sizes; (void)n_in; (void)out_size;
  const float* x  = (const float*)d_in[0];   // (B=8, D=1024, N=1024)
  const float* la = (const float*)d_in[1];   // (N, N)
  const float* u  = (const float*)d_in[2];   // (S=4, B=8, N, N)
  float* out = (float*)d_out;                // (S, B, D, N)

  char* ws = (char*)d_ws;
  float* K            = (float*)(ws);                       // 128 MiB fp32 kernel matrices
  unsigned short* Pt  = (unsigned short*)(ws + 134217728);  // 64 MiB bf16 P^T
  unsigned short* xb  = (unsigned short*)(ws + 201326592);  // 16 MiB bf16 x
  float* uu           = (float*)(ws + 218103808);           // 128 KiB row potentials
  float* vv           = (float*)(ws + 218234880);           // 128 KiB col potentials
  float* pv           = (float*)(ws + 218365952);           // 512 KiB col partials
  if (ws_size < 218890240) return;  // fail loudly rather than corrupt

  gumbel_k<<<32768, 256, 0, stream>>>((const float4*)u, (const float4*)la, (float4*)K, uu);
  cvt_x<<<8192, 256, 0, stream>>>((const float4*)x, xb);

  for (int it = 0; it < NITERS; ++it) {
    col_pass<<<512, 256, 0, stream>>>(K, uu, pv);
    col_reduce<<<32, 256, 0, stream>>>((const float4*)pv, (float4*)vv);
    row_pass<<<8192, 256, 0, stream>>>(K, vv, uu);
  }

  make_pt<<<8192, 256, 0, stream>>>(K, uu, vv, Pt);

  dim3 g(64, 32);
  gemm_bf16<<<g, 256, 0, stream>>>(xb, Pt, out);
}

// Round 3
// 482.555 us; speedup vs baseline: 2.3760x; 2.3760x over previous
//
#include <hip/hip_runtime.h>

#define EPS 1e-10f
#define NITERS 20
#define NN (1024*1024)

typedef __attribute__((ext_vector_type(8))) short bf16x8;
typedef __attribute__((ext_vector_type(4))) float f32x4;

__device__ __forceinline__ unsigned short f2bf(float f) {
  unsigned int x = __builtin_bit_cast(unsigned int, f);
  x += 0x7fffu + ((x >> 16) & 1u);   // round-to-nearest-even
  return (unsigned short)(x >> 16);
}
__device__ __forceinline__ float bf2f(short s) {
  return __builtin_bit_cast(float, ((unsigned int)(unsigned short)s) << 16);
}

// ---------------------------------------------------------------------------
// K = exp(la)/(EPS - log(u+EPS)) in bf16, + column-sum partials (c1, u-pot=1).
// grid 512: sb = bx>>4 (32 matrices), ch = bx&15 (64-row chunk). 256 thr.
// lane l owns cols [16l,16l+16); wave w rows {r0+4p+w}.
__global__ __launch_bounds__(256) void gumbel_colpass(const float* __restrict__ u,
                                                      const float* __restrict__ la,
                                                      unsigned short* __restrict__ Kb,
                                                      float* __restrict__ pv) {
  int bx = blockIdx.x;
  int sb = bx >> 4, ch = bx & 15;
  int tid = threadIdx.x, l = tid & 63, w = tid >> 6;
  int r0 = ch << 6;
  const float* ub = u + (size_t)sb * NN;
  float colacc[16];
#pragma unroll
  for (int k = 0; k < 16; ++k) colacc[k] = 0.f;

#pragma unroll 1
  for (int p = 0; p < 16; ++p) {
    int row = r0 + (p << 2) + w;
    const float4* u4 = (const float4*)(ub + (size_t)row * 1024 + l * 16);
    const float4* la4 = (const float4*)(la + (size_t)row * 1024 + l * 16);
    float kf[16];
#pragma unroll
    for (int q = 0; q < 4; ++q) {
      float4 uv = u4[q];
      float4 lv = la4[q];
      kf[q*4+0] = expf(lv.x) / (EPS - logf(uv.x + EPS));
      kf[q*4+1] = expf(lv.y) / (EPS - logf(uv.y + EPS));
      kf[q*4+2] = expf(lv.z) / (EPS - logf(uv.z + EPS));
      kf[q*4+3] = expf(lv.w) / (EPS - logf(uv.w + EPS));
    }
    bf16x8 o0, o1;
#pragma unroll
    for (int j = 0; j < 8; ++j) {
      o0[j] = (short)f2bf(kf[j]);
      o1[j] = (short)f2bf(kf[8 + j]);
      colacc[j] += kf[j];
      colacc[8 + j] += kf[8 + j];
    }
    bf16x8* kp = (bf16x8*)(Kb + (size_t)sb * NN + (size_t)row * 1024 + l * 16);
    kp[0] = o0; kp[1] = o1;
  }

  __shared__ float cacc[4][1024];
#pragma unroll
  for (int k = 0; k < 16; ++k) cacc[w][l * 16 + k] = colacc[k];
  __syncthreads();
  // thread tid -> cols [4tid,4tid+4)
  float4 s0 = *(float4*)&cacc[0][tid * 4];
  float4 s1 = *(float4*)&cacc[1][tid * 4];
  float4 s2 = *(float4*)&cacc[2][tid * 4];
  float4 s3 = *(float4*)&cacc[3][tid * 4];
  float4 s;
  s.x = s0.x + s1.x + s2.x + s3.x; s.y = s0.y + s1.y + s2.y + s3.y;
  s.z = s0.z + s1.z + s2.z + s3.z; s.w = s0.w + s1.w + s2.w + s3.w;
  ((float4*)pv)[((sb << 4) + ch) * 256 + tid] = s;
}

// ---------------------------------------------------------------------------
// Fused: v = 1/reduce(pv_in); u_i = 1/(K_i . v) for the chunk's 64 rows;
// pv_out[chunk] = partial col sums of K^T u. One K read per iteration.
__global__ __launch_bounds__(256) void sinkhorn_fused(const unsigned short* __restrict__ Kb,
                                                      const float* __restrict__ pv_in,
                                                      float* __restrict__ pv_out) {
  int bx = blockIdx.x;
  int sb = bx >> 4, ch = bx & 15;
  int tid = threadIdx.x, l = tid & 63, w = tid >> 6;
  int r0 = ch << 6;
  __shared__ float smem[4][1024];

  // phase 1: reduce 16 partials -> v (cols 4tid..4tid+3), share via LDS
  {
    const float4* p4 = (const float4*)pv_in + (sb << 12);  // sb*16*256
    float4 s = make_float4(0.f, 0.f, 0.f, 0.f);
#pragma unroll
    for (int c = 0; c < 16; ++c) {
      float4 a = p4[c * 256 + tid];
      s.x += a.x; s.y += a.y; s.z += a.z; s.w += a.w;
    }
    float4 v4;
    v4.x = 1.f / s.x; v4.y = 1.f / s.y; v4.z = 1.f / s.z; v4.w = 1.f / s.w;
    *(float4*)&smem[0][tid * 4] = v4;
  }
  __syncthreads();
  float vreg[16];
#pragma unroll
  for (int k = 0; k < 16; ++k) vreg[k] = smem[0][l * 16 + k];
  __syncthreads();   // smem about to be reused as col accumulator

  // phase 2: rows; dot -> u_i ; col partial accumulate (all in registers)
  const unsigned short* Ks = Kb + (size_t)sb * NN;
  float colacc[16];
#pragma unroll
  for (int k = 0; k < 16; ++k) colacc[k] = 0.f;

#pragma unroll 2
  for (int p = 0; p < 16; ++p) {
    int row = r0 + (p << 2) + w;
    const bf16x8* kp = (const bf16x8*)(Ks + (size_t)row * 1024 + l * 16);
    bf16x8 k0 = kp[0], k1 = kp[1];
    float kf[16];
#pragma unroll
    for (int j = 0; j < 8; ++j) { kf[j] = bf2f(k0[j]); kf[8 + j] = bf2f(k1[j]); }
    float dot = 0.f;
#pragma unroll
    for (int k = 0; k < 16; ++k) dot += kf[k] * vreg[k];
#pragma unroll
    for (int m = 1; m < 64; m <<= 1) dot += __shfl_xor(dot, m, 64);
    float ui = 1.0f / dot;
#pragma unroll
    for (int k = 0; k < 16; ++k) colacc[k] += kf[k] * ui;
  }

  // phase 3: combine 4 waves, write pv_out
#pragma unroll
  for (int k = 0; k < 16; ++k) smem[w][l * 16 + k] = colacc[k];
  __syncthreads();
  float4 s0 = *(float4*)&smem[0][tid * 4];
  float4 s1 = *(float4*)&smem[1][tid * 4];
  float4 s2 = *(float4*)&smem[2][tid * 4];
  float4 s3 = *(float4*)&smem[3][tid * 4];
  float4 s;
  s.x = s0.x + s1.x + s2.x + s3.x; s.y = s0.y + s1.y + s2.y + s3.y;
  s.z = s0.z + s1.z + s2.z + s3.z; s.w = s0.w + s1.w + s2.w + s3.w;
  ((float4*)pv_out)[((sb << 4) + ch) * 256 + tid] = s;
}

// ---------------------------------------------------------------------------
// Final: v = 1/reduce(pv); u_i = 1/(K_i . v); Pt[m][n] = K[n][m]*u[n]*v[m] (bf16).
__global__ __launch_bounds__(256) void rowpass_pt(const unsigned short* __restrict__ Kb,
                                                  const float* __restrict__ pv_in,
                                                  unsigned short* __restrict__ Pt) {
  int bx = blockIdx.x;
  int sb = bx >> 4, ch = bx & 15;
  int tid = threadIdx.x, l = tid & 63, w = tid >> 6;
  int r0 = ch << 6;
  __shared__ float v_lds[1024];
  __shared__ float u_lds[64];
  __shared__ unsigned short tile[64][66];

  {
    const float4* p4 = (const float4*)pv_in + (sb << 12);
    float4 s = make_float4(0.f, 0.f, 0.f, 0.f);
#pragma unroll
    for (int c = 0; c < 16; ++c) {
      float4 a = p4[c * 256 + tid];
      s.x += a.x; s.y += a.y; s.z += a.z; s.w += a.w;
    }
    float4 v4;
    v4.x = 1.f / s.x; v4.y = 1.f / s.y; v4.z = 1.f / s.z; v4.w = 1.f / s.w;
    *(float4*)&v_lds[tid * 4] = v4;
  }
  __syncthreads();
  float vreg[16];
#pragma unroll
  for (int k = 0; k < 16; ++k) vreg[k] = v_lds[l * 16 + k];

  const unsigned short* Ks = Kb + (size_t)sb * NN;
#pragma unroll 2
  for (int p = 0; p < 16; ++p) {
    int row = r0 + (p << 2) + w;
    const bf16x8* kp = (const bf16x8*)(Ks + (size_t)row * 1024 + l * 16);
    bf16x8 k0 = kp[0], k1 = kp[1];
    float dot = 0.f;
#pragma unroll
    for (int j = 0; j < 8; ++j) dot += bf2f(k0[j]) * vreg[j] + bf2f(k1[j]) * vreg[8 + j];
#pragma unroll
    for (int m = 1; m < 64; m <<= 1) dot += __shfl_xor(dot, m, 64);
    if (l == 0) u_lds[(p << 2) + w] = 1.0f / dot;
  }
  __syncthreads();

  // emit Pt: for n in [r0,r0+64), all m; 16 m-tiles of 64x64 via LDS transpose
  unsigned short* Pb = Pt + (size_t)sb * NN;
  int c = tid & 63, r4 = tid >> 6;
  for (int mt = 0; mt < 16; ++mt) {
    int m0 = mt << 6;
#pragma unroll
    for (int p = 0; p < 16; ++p) {
      int rr = (p << 2) + r4;
      float val = bf2f((short)Ks[(size_t)(r0 + rr) * 1024 + m0 + c]) * u_lds[rr] * v_lds[m0 + c];
      tile[rr][c] = f2bf(val);
    }
    __syncthreads();
#pragma unroll
    for (int p = 0; p < 16; ++p) {
      int rr = (p << 2) + r4;
      Pb[(size_t)(m0 + rr) * 1024 + r0 + c] = tile[c][rr];
    }
    __syncthreads();
  }
}

// ---------------------------------------------------------------------------
__global__ __launch_bounds__(256) void cvt_x(const float4* __restrict__ x4,
                                             unsigned short* __restrict__ xb) {
  int gid = blockIdx.x * 256 + threadIdx.x;      // 2,097,152 float4s
  float4 v = x4[gid];
  ushort4 o;
  o.x = f2bf(v.x); o.y = f2bf(v.y); o.z = f2bf(v.z); o.w = f2bf(v.w);
  *(ushort4*)&xb[(size_t)gid * 4] = o;
}

// C[d][m] = sum_n A[d][n] * B[n][m]; A = xb (row-major), Bt = P^T.
// 128x128 tile, 4 waves, 16x16x32 MFMA, global_load_lds(16B), XCD swizzle.
__global__ __launch_bounds__(256) void gemm_bf16(const unsigned short* __restrict__ xb,
                                                 const unsigned short* __restrict__ Pt,
                                                 float* __restrict__ out) {
  int bid = blockIdx.x;                          // 2048 = 8 XCD * 256
  int lid = (bid & 7) * 256 + (bid >> 3);        // bijective XCD swizzle
  int sb = lid >> 6;
  int tm = (lid >> 3) & 7;
  int tn = lid & 7;
  int b = sb & 7;
  const unsigned short* A = xb + (size_t)b * NN;
  const unsigned short* Bt = Pt + (size_t)sb * NN;
  float* C = out + (size_t)sb * NN;

  __shared__ unsigned short lA[128 * 32];
  __shared__ unsigned short lB[128 * 32];

  int tid = threadIdx.x;
  int lane = tid & 63;
  int w = tid >> 6;
  int wm = (w >> 1) << 6;
  int wn = (w & 1) << 6;

  f32x4 acc[4][4] = {};

  int lr = tid >> 2;
  int lk = (tid & 3) << 3;
  const unsigned short* gA0 = A + (size_t)(tm * 128 + lr) * 1024 + lk;
  const unsigned short* gB0 = Bt + (size_t)(tn * 128 + lr) * 1024 + lk;

  for (int k0 = 0; k0 < 1024; k0 += 32) {
    __builtin_amdgcn_global_load_lds((const __attribute__((address_space(1))) void*)(gA0 + k0),
                                     (__attribute__((address_space(3))) void*)&lA[tid * 8], 16, 0, 0);
    __builtin_amdgcn_global_load_lds((const __attribute__((address_space(1))) void*)(gA0 + 64 * 1024 + k0),
                                     (__attribute__((address_space(3))) void*)&lA[2048 + tid * 8], 16, 0, 0);
    __builtin_amdgcn_global_load_lds((const __attribute__((address_space(1))) void*)(gB0 + k0),
                                     (__attribute__((address_space(3))) void*)&lB[tid * 8], 16, 0, 0);
    __builtin_amdgcn_global_load_lds((const __attribute__((address_space(1))) void*)(gB0 + 64 * 1024 + k0),
                                     (__attribute__((address_space(3))) void*)&lB[2048 + tid * 8], 16, 0, 0);
    __syncthreads();

    int kg = (lane >> 4) << 3;
    int rr = lane & 15;
    bf16x8 af[4], bfr[4];
#pragma unroll
    for (int mt = 0; mt < 4; ++mt)
      af[mt] = *(const bf16x8*)&lA[(wm + mt * 16 + rr) * 32 + kg];
#pragma unroll
    for (int nt = 0; nt < 4; ++nt)
      bfr[nt] = *(const bf16x8*)&lB[(wn + nt * 16 + rr) * 32 + kg];
#pragma unroll
    for (int mt = 0; mt < 4; ++mt)
#pragma unroll
      for (int nt = 0; nt < 4; ++nt)
        acc[mt][nt] = __builtin_amdgcn_mfma_f32_16x16x32_bf16(af[mt], bfr[nt], acc[mt][nt], 0, 0, 0);
    __syncthreads();
  }

  int col0 = lane & 15;
  int row0 = (lane >> 4) << 2;
#pragma unroll
  for (int mt = 0; mt < 4; ++mt) {
#pragma unroll
    for (int nt = 0; nt < 4; ++nt) {
      int row = tm * 128 + wm + mt * 16 + row0;
      int col = tn * 128 + wn + nt * 16 + col0;
#pragma unroll
      for (int r = 0; r < 4; ++r)
        C[(size_t)(row + r) * 1024 + col] = acc[mt][nt][r];
    }
  }
}

extern "C" void kernel_launch(void* const* d_in, const int* in_sizes, int n_in,
                              void* d_out, int out_size, void* d_ws, size_t ws_size,
                              hipStream_t stream) {
  (void)in_sizes; (void)n_in; (void)out_size;
  const float* x  = (const float*)d_in[0];   // (B=8, D=1024, N=1024)
  const float* la = (const float*)d_in[1];   // (N, N)
  const float* u  = (const float*)d_in[2];   // (S=4, B=8, N, N)
  float* out = (float*)d_out;                // (S, B, D, N)

  char* ws = (char*)d_ws;
  unsigned short* Kb = (unsigned short*)(ws);               // 64 MiB bf16 K
  unsigned short* Pt = (unsigned short*)(ws + 67108864);    // 64 MiB bf16 P^T
  unsigned short* xb = (unsigned short*)(ws + 134217728);   // 16 MiB bf16 x
  float* pvA         = (float*)(ws + 150994944);            // 2 MiB col partials
  float* pvB         = (float*)(ws + 153092096);            // 2 MiB col partials
  if (ws_size < 155189248) return;  // fail loudly rather than corrupt

  gumbel_colpass<<<512, 256, 0, stream>>>(u, la, Kb, pvA);
  cvt_x<<<8192, 256, 0, stream>>>((const float4*)x, xb);

  float* pin = pvA;
  float* pout = pvB;
  for (int t = 1; t <= NITERS - 1; ++t) {       // 19 fused row+col passes
    sinkhorn_fused<<<512, 256, 0, stream>>>(Kb, pin, pout);
    float* tmp = pin; pin = pout; pout = tmp;
  }
  rowpass_pt<<<512, 256, 0, stream>>>(Kb, pin, Pt);  // r20 + P^T emit

  gemm_bf16<<<2048, 256, 0, stream>>>(xb, Pt, out);
}